// Round 11
// baseline (493.452 us; speedup 1.0000x reference)
//
#include <hip/hip_runtime.h>
#include <hip/hip_bf16.h>
#include <hip/hip_cooperative_groups.h>

namespace cg = cooperative_groups;

#define B_SZ 128
#define IN_CAPS 1152
#define N_CAPS 16
#define DIM 16

#define IPB 18                        // i's per ic-worker: 64 workers x 18 = 1152 exactly
#define ICW 64                        // ic workers
#define OUT_ELEMS (B_SZ * N_CAPS * DIM)   // 32768
// LDS hat tile (bf16 pairs, uint units): [slot(2)][b(16)][n(16)][ep(8)]
#define NSTRU 12
#define BSTRU 196
#define SLOTU (16 * BSTRU)            // 3136 uints = 12.5 KB/slot

typedef __attribute__((ext_vector_type(8))) short bf16x8;
typedef __attribute__((ext_vector_type(4))) float f32x4;

__device__ __forceinline__ unsigned short f2bf(float f) {   // RNE
    unsigned u = __float_as_uint(f);
    u = u + 0x7fffu + ((u >> 16) & 1u);
    return (unsigned short)(u >> 16);
}
__device__ __forceinline__ unsigned pk2(float lo, float hi) {
    return ((unsigned)f2bf(hi) << 16) | f2bf(lo);
}
__device__ __forceinline__ unsigned cvtpk(float lo, float hi) {
    union { __hip_bfloat162 h; unsigned u; } c;
    c.h = __float22bfloat162_rn(make_float2(lo, hi));
    return c.u;
}
__device__ __forceinline__ float dpp_sum16(float v) {
    v += __int_as_float(__builtin_amdgcn_update_dpp(0, __float_as_int(v), 0xB1, 0xF, 0xF, true));
    v += __int_as_float(__builtin_amdgcn_update_dpp(0, __float_as_int(v), 0x4E, 0xF, 0xF, true));
    v += __int_as_float(__builtin_amdgcn_update_dpp(0, __float_as_int(v), 0x124, 0xF, 0xF, true));
    v += __int_as_float(__builtin_amdgcn_update_dpp(0, __float_as_int(v), 0x128, 0xF, 0xF, true));
    return v;
}
__device__ __forceinline__ float dpp_sum8(float v) {
    v += __int_as_float(__builtin_amdgcn_update_dpp(0, __float_as_int(v), 0xB1, 0xF, 0xF, true));
    v += __int_as_float(__builtin_amdgcn_update_dpp(0, __float_as_int(v), 0x4E, 0xF, 0xF, true));
    v += __int_as_float(__builtin_amdgcn_update_dpp(0, __float_as_int(v), 0x141, 0xF, 0xF, true));
    return v;
}

// Produce one i of hat into an LDS slot (R10-proven). A = W (m=e), B = x
// (col=b, k>=8 zeroed). D: col=b, reg=e(4q+r) -> pack bf16 -> ds_write_b64.
__device__ __forceinline__ void produce_i(
    const unsigned short* __restrict__ XT, const unsigned short* __restrict__ WB,
    unsigned* __restrict__ slot, int i, int bt, int w, int q, int em)
{
    uint4 xu = {0u, 0u, 0u, 0u};
    if (q == 0)
        xu = *(const uint4*)(XT + ((size_t)i * B_SZ + bt * 16 + em) * 8);
    union { uint4 u; bf16x8 v; } bx; bx.u = xu;
    #pragma unroll
    for (int np = 0; np < 4; ++np) {
        const int nn = 4 * w + np;
        bf16x8 av = *(const bf16x8*)(WB + (((size_t)nn * IN_CAPS + i) * DIM + em) * 8);
        f32x4 cz = {0.f, 0.f, 0.f, 0.f};
        f32x4 d = __builtin_amdgcn_mfma_f32_16x16x32_bf16(av, bx.v, cz, 0, 0, 0);
        uint2 o = {cvtpk(d[0], d[1]), cvtpk(d[2], d[3])};
        *(uint2*)(slot + (size_t)em * BSTRU + nn * NSTRU + 2 * q) = o;
    }
}

// One routing pass for this block's (bt, ic): R10 internals (dbuf, DPP softmax,
// e-in-thread consumer), IPB=18 chunks, bf16 partial slice out.
template<int MODE>
__device__ void pass_phase(
    const unsigned short* __restrict__ XT, const unsigned short* __restrict__ WB,
    const float* __restrict__ Bb,
    const float* __restrict__ accA, const float* __restrict__ accB,
    unsigned short* __restrict__ partial, unsigned* __restrict__ hatp,
    int bt, int ic, int tid)
{
    const int lane = tid & 63;
    const int w    = tid >> 6;
    const int em   = lane & 15;
    const int q    = lane >> 4;
    const int n    = em;
    const int b_loc = 4 * w + q;
    const int b_glb = bt * 16 + b_loc;
    const int i0   = ic * IPB;

    float pr[16];
    if (MODE > 0) {
        const float4* bbp = (const float4*)(Bb + (n << 4));
        const float4* ap  = (const float4*)(accA + ((size_t)b_glb << 8) + (n << 4));
        float s[16], s2 = 0.f;
        #pragma unroll
        for (int k4 = 0; k4 < 4; ++k4) {
            float4 a = ap[k4], bb = bbp[k4];
            s[4*k4+0] = a.x + bb.x; s[4*k4+1] = a.y + bb.y;
            s[4*k4+2] = a.z + bb.z; s[4*k4+3] = a.w + bb.w;
        }
        #pragma unroll
        for (int e = 0; e < 16; ++e) s2 = fmaf(s[e], s[e], s2);
        float sc = sqrtf(s2) / (1.0f + s2);
        #pragma unroll
        for (int e = 0; e < 16; ++e) pr[e] = s[e] * sc;
        if (MODE == 2) {
            const float4* ap2 = (const float4*)(accB + ((size_t)b_glb << 8) + (n << 4));
            float t[16], t2 = 0.f;
            #pragma unroll
            for (int k4 = 0; k4 < 4; ++k4) {
                float4 a = ap2[k4], bb = bbp[k4];
                t[4*k4+0] = a.x + bb.x; t[4*k4+1] = a.y + bb.y;
                t[4*k4+2] = a.z + bb.z; t[4*k4+3] = a.w + bb.w;
            }
            #pragma unroll
            for (int e = 0; e < 16; ++e) t2 = fmaf(t[e], t[e], t2);
            float sc2 = sqrtf(t2) / (1.0f + t2);
            #pragma unroll
            for (int e = 0; e < 16; ++e) pr[e] = fmaf(t[e], sc2, pr[e]);
        }
        #pragma unroll
        for (int e = 0; e < 16; ++e)
            asm volatile("" : "+v"(pr[e]));
    }

    float acc[16];
    #pragma unroll
    for (int e = 0; e < 16; ++e) acc[e] = 0.f;

    produce_i(XT, WB, hatp, i0, bt, w, q, em);

    #pragma unroll 1
    for (int ch = 0; ch < IPB; ++ch) {
        __syncthreads();
        if (ch + 1 < IPB)
            produce_i(XT, WB, hatp + ((ch + 1) & 1) * SLOTU, i0 + ch + 1, bt, w, q, em);

        const unsigned* rowp = hatp + (ch & 1) * SLOTU + (size_t)b_loc * BSTRU + n * NSTRU;
        uint4 u0 = *(const uint4*)rowp;
        uint4 u1 = *(const uint4*)(rowp + 4);
        float h[16];
        {
            unsigned uu[8] = {u0.x, u0.y, u0.z, u0.w, u1.x, u1.y, u1.z, u1.w};
            #pragma unroll
            for (int j = 0; j < 8; ++j) {
                h[2*j]   = __uint_as_float(uu[j] << 16);
                h[2*j+1] = __uint_as_float(uu[j] & 0xFFFF0000u);
            }
        }
        float c;
        if (MODE > 0) {
            float lg = 0.f;
            #pragma unroll
            for (int e = 0; e < 16; ++e) lg = fmaf(pr[e], h[e], lg);
            float p = __expf(lg);
            float z = dpp_sum16(p);
            c = p * __builtin_amdgcn_rcpf(z);
        } else {
            c = 0.0625f;
        }
        #pragma unroll
        for (int e = 0; e < 16; ++e) acc[e] = fmaf(c, h[e], acc[e]);
    }
    __syncthreads();   // last consume done before anything re-touches LDS

    unsigned short* pp = partial + (((size_t)ic * B_SZ + b_glb) << 8) + (n << 4);
    uint4 o0 = {pk2(acc[0], acc[1]),   pk2(acc[2], acc[3]),
                pk2(acc[4], acc[5]),   pk2(acc[6], acc[7])};
    uint4 o1 = {pk2(acc[8], acc[9]),   pk2(acc[10], acc[11]),
                pk2(acc[12], acc[13]), pk2(acc[14], acc[15])};
    *(uint4*)pp = o0;
    *(uint4*)(pp + 8) = o1;
}

// Reduce 64 bf16 slices (blocks 0..255; 64 uint positions each; 4 grps x 16 slices).
template<bool FINAL>
__device__ void reduce_phase(const unsigned* __restrict__ partial,
                             const float* __restrict__ Bb,
                             float2* __restrict__ acc, float2* __restrict__ out,
                             int blk, int tid, unsigned* __restrict__ lds)
{
    const int ps  = tid & 63;
    const int grp = tid >> 6;
    const int pos = blk * 64 + ps;               // uint index in [0, 16384)

    float t0 = 0.f, t1 = 0.f;
    #pragma unroll
    for (int k = 0; k < ICW / 4; ++k) {
        unsigned u = partial[(size_t)(grp * (ICW / 4) + k) * (OUT_ELEMS / 2) + pos];
        t0 += __uint_as_float(u << 16);
        t1 += __uint_as_float(u & 0xFFFF0000u);
    }
    float2 (*red)[64] = (float2(*)[64])lds;
    red[grp][ps] = make_float2(t0, t1);
    __syncthreads();

    if (tid < 64) {
        float2 a = red[0][ps], b = red[1][ps], c = red[2][ps], d = red[3][ps];
        float v0 = a.x + b.x + c.x + d.x;
        float v1 = a.y + b.y + c.y + d.y;
        if (!FINAL) {
            acc[pos] = make_float2(v0, v1);
        } else {
            const int n = (pos >> 3) & 15, ep = pos & 7;
            float2 bb = *(const float2*)(Bb + n * 16 + 2 * ep);
            v0 += bb.x; v1 += bb.y;
            float s2 = dpp_sum8(v0 * v0 + v1 * v1);
            float sc = sqrtf(s2) / (1.0f + s2);
            out[pos] = make_float2(v0 * sc, v1 * sc);
        }
    }
    __syncthreads();
}

// ---- the whole op: convert -> (pass -> reduce) x3, grid-synced ----
// R8-R10 lesson: 7-launch split left the passes stuck at ~40us with counters
// invisible under harness fills. One cooperative kernel removes every launch
// boundary and gives a single >100us dispatch we can actually profile.
__global__ __launch_bounds__(256)
void caps_all(const float* __restrict__ x, const float* __restrict__ W,
              const float* __restrict__ Bb,
              unsigned short* __restrict__ WB, unsigned short* __restrict__ XT,
              float* __restrict__ accA, float* __restrict__ accB,
              unsigned short* __restrict__ partial, float2* __restrict__ out)
{
    __shared__ unsigned lds[2 * SLOTU];          // 25.1 KB (pass dbuf; reduce aliases)
    const int p   = blockIdx.x;                  // 512 blocks (2/CU -> coop-safe)
    const int tid = threadIdx.x;
    cg::grid_group grid = cg::this_grid();

    // phase C: convert W -> WB bf16 (units 0..1151), x -> XT[i][b][d] bf16 (1152..1727)
    for (int u = p; u < 1728; u += 512) {
        if (u < 1152) {
            size_t g = (size_t)u * 256 + tid;
            const float4* src = (const float4*)(W + g * 8);
            float4 a = src[0], b = src[1];
            uint4 o = {pk2(a.x, a.y), pk2(a.z, a.w), pk2(b.x, b.y), pk2(b.z, b.w)};
            *(uint4*)(WB + g * 8) = o;
        } else {
            const int bx = u - 1152;
            const int i = bx * 2 + (tid >> 7);
            const int b = tid & 127;
            const float4* src = (const float4*)(x + ((size_t)b * IN_CAPS + i) * 8);
            float4 a = src[0], c = src[1];
            uint4 o = {pk2(a.x, a.y), pk2(a.z, a.w), pk2(c.x, c.y), pk2(c.z, c.w)};
            *(uint4*)(XT + ((size_t)i * B_SZ + b) * 8) = o;
        }
    }
    grid.sync();

    const int bt = p >> 6;                       // 0..7
    const int ic = p & 63;                       // 0..63

    pass_phase<0>(XT, WB, Bb, accA, accB, partial, lds, bt, ic, tid);
    grid.sync();
    if (p < 256) reduce_phase<false>((const unsigned*)partial, Bb, (float2*)accA, nullptr, p, tid, lds);
    grid.sync();

    pass_phase<1>(XT, WB, Bb, accA, accB, partial, lds, bt, ic, tid);
    grid.sync();
    if (p < 256) reduce_phase<false>((const unsigned*)partial, Bb, (float2*)accB, nullptr, p, tid, lds);
    grid.sync();

    pass_phase<2>(XT, WB, Bb, accA, accB, partial, lds, bt, ic, tid);
    grid.sync();
    if (p < 256) reduce_phase<true>((const unsigned*)partial, Bb, nullptr, out, p, tid, lds);
}

extern "C" void kernel_launch(void* const* d_in, const int* in_sizes, int n_in,
                              void* d_out, int out_size, void* d_ws, size_t ws_size,
                              hipStream_t stream)
{
    const float* x  = (const float*)d_in[0];   // [128,1152,8]
    const float* W  = (const float*)d_in[1];   // [16,1152,16,8]
    const float* Bb = (const float*)d_in[2];   // [16,16]
    float2* out = (float2*)d_out;              // [128,16,16] fp32

    float* accA = (float*)d_ws;                                   // 128 KB
    float* accB = accA + OUT_ELEMS;                               // 128 KB
    unsigned short* WB = (unsigned short*)(accB + OUT_ELEMS);     // 4.72 MB
    unsigned short* XT = WB + (size_t)N_CAPS * IN_CAPS * DIM * 8; // 2.36 MB
    unsigned short* partial = XT + (size_t)B_SZ * IN_CAPS * 8;    // 64 x 64 KB = 4.2 MB

    void* args[] = { (void*)&x, (void*)&W, (void*)&Bb, (void*)&WB, (void*)&XT,
                     (void*)&accA, (void*)&accB, (void*)&partial, (void*)&out };
    hipLaunchCooperativeKernel((const void*)caps_all, dim3(512), dim3(256),
                               args, 0, stream);
}

// Round 12
// 278.837 us; speedup vs baseline: 1.7697x; 1.7697x over previous
//
#include <hip/hip_runtime.h>
#include <hip/hip_bf16.h>

#define B_SZ 128
#define IN_CAPS 1152
#define N_CAPS 16
#define DIM 16

#define IPB 4                         // i's per pass-block (short chunks -> big grid)
#define ICN (IN_CAPS / IPB)           // 288 partial slices
#define OUT_ELEMS (B_SZ * N_CAPS * DIM)   // 32768
// LDS hat tile (bf16 pairs, uint units): [slot(2)][b(16)][n(16)][ep(8)]
#define NSTRU 12
#define BSTRU 196
#define SLOTU (16 * BSTRU)            // 3136 uints = 12.5 KB/slot

typedef __attribute__((ext_vector_type(8))) short bf16x8;
typedef __attribute__((ext_vector_type(4))) float f32x4;

__device__ __forceinline__ unsigned short f2bf(float f) {   // RNE
    unsigned u = __float_as_uint(f);
    u = u + 0x7fffu + ((u >> 16) & 1u);
    return (unsigned short)(u >> 16);
}
__device__ __forceinline__ unsigned pk2(float lo, float hi) {
    return ((unsigned)f2bf(hi) << 16) | f2bf(lo);
}
__device__ __forceinline__ unsigned cvtpk(float lo, float hi) {
    union { __hip_bfloat162 h; unsigned u; } c;
    c.h = __float22bfloat162_rn(make_float2(lo, hi));
    return c.u;
}
__device__ __forceinline__ float dpp_sum16(float v) {
    v += __int_as_float(__builtin_amdgcn_update_dpp(0, __float_as_int(v), 0xB1, 0xF, 0xF, true));
    v += __int_as_float(__builtin_amdgcn_update_dpp(0, __float_as_int(v), 0x4E, 0xF, 0xF, true));
    v += __int_as_float(__builtin_amdgcn_update_dpp(0, __float_as_int(v), 0x124, 0xF, 0xF, true));
    v += __int_as_float(__builtin_amdgcn_update_dpp(0, __float_as_int(v), 0x128, 0xF, 0xF, true));
    return v;
}
__device__ __forceinline__ float dpp_sum8(float v) {
    v += __int_as_float(__builtin_amdgcn_update_dpp(0, __float_as_int(v), 0xB1, 0xF, 0xF, true));
    v += __int_as_float(__builtin_amdgcn_update_dpp(0, __float_as_int(v), 0x4E, 0xF, 0xF, true));
    v += __int_as_float(__builtin_amdgcn_update_dpp(0, __float_as_int(v), 0x141, 0xF, 0xF, true));
    return v;
}

// ---- prep (fused): blocks [0,1152): W -> WB bf16; [1152,1728): x -> XT[i][b][d] bf16 ----
__global__ __launch_bounds__(256)
void conv_xw(const float* __restrict__ W, const float* __restrict__ x,
             unsigned short* __restrict__ WB, unsigned short* __restrict__ XT)
{
    const int tid = threadIdx.x;
    if (blockIdx.x < 1152) {
        size_t g = (size_t)blockIdx.x * 256 + tid;
        const float4* src = (const float4*)(W + g * 8);
        float4 a = src[0], b = src[1];
        uint4 o = {pk2(a.x, a.y), pk2(a.z, a.w), pk2(b.x, b.y), pk2(b.z, b.w)};
        *(uint4*)(WB + g * 8) = o;
    } else {
        const int bx = blockIdx.x - 1152;
        const int i = bx * 2 + (tid >> 7);
        const int b = tid & 127;
        const float4* src = (const float4*)(x + ((size_t)b * IN_CAPS + i) * 8);
        float4 a = src[0], c = src[1];
        uint4 o = {pk2(a.x, a.y), pk2(a.z, a.w), pk2(c.x, c.y), pk2(c.z, c.w)};
        *(uint4*)(XT + ((size_t)i * B_SZ + b) * 8) = o;
    }
}

// Prefetched operands for one i (VGPR-resident while in flight)
struct Pre { uint4 xu; uint4 wb[4]; };

__device__ __forceinline__ void load_i(
    const unsigned short* __restrict__ XT, const unsigned short* __restrict__ WB,
    Pre& p, int i, int bt, int w, int q, int em)
{
    p.xu = make_uint4(0u, 0u, 0u, 0u);
    if (q == 0)
        p.xu = *(const uint4*)(XT + ((size_t)i * B_SZ + bt * 16 + em) * 8);
    #pragma unroll
    for (int np = 0; np < 4; ++np) {
        const int nn = 4 * w + np;
        p.wb[np] = *(const uint4*)(WB + (((size_t)nn * IN_CAPS + i) * DIM + em) * 8);
    }
}

// MFMA + LDS commit (R10-proven layout): A = W (m=e), B = x (col=b, k>=8 zeroed);
// D: col=b, regs = 4 e's -> pack bf16 -> ds_write_b64.
__device__ __forceinline__ void commit_i(const Pre& p, unsigned* __restrict__ slot,
                                         int w, int q, int em)
{
    union { uint4 u; bf16x8 v; } bx; bx.u = p.xu;
    #pragma unroll
    for (int np = 0; np < 4; ++np) {
        const int nn = 4 * w + np;
        union { uint4 u; bf16x8 v; } ax; ax.u = p.wb[np];
        f32x4 cz = {0.f, 0.f, 0.f, 0.f};
        f32x4 d = __builtin_amdgcn_mfma_f32_16x16x32_bf16(ax.v, bx.v, cz, 0, 0, 0);
        uint2 o = {cvtpk(d[0], d[1]), cvtpk(d[2], d[3])};
        *(uint2*)(slot + (size_t)em * BSTRU + nn * NSTRU + 2 * q) = o;
    }
}

// ---- fused routing pass ----
// R11 counters (VALUBusy 6%, MfmaUtil 0.7%, HBM 1.5%, all idle): the chunk loop
// is LATENCY-serial (~600-900 cyc exposed global-load latency per chunk); wall
// time ~ 1/resident-waves. Fix: (1) IPB=4 -> 2304 blocks, LDS-limited 6
// blocks/CU (was grid-limited 4.5); (2) 1-deep REGISTER prefetch: loads for
// chunk k+2 issue while chunk k is consumed, so only ~commit+consume cycles of
// latency remain exposed. Internals (MFMA layout, DPP softmax, bf16 partial)
// R10-proven.
// MODE 0: c=1/16.  MODE 1: pr = squash(accA+B).  MODE 2: pr = sq(accA+B)+sq(accB+B).
template<int MODE>
__global__ __launch_bounds__(256)
void caps_pass(const unsigned short* __restrict__ XT, const unsigned short* __restrict__ WB,
               const float* __restrict__ Bb,
               const float* __restrict__ accA, const float* __restrict__ accB,
               unsigned short* __restrict__ partial)
{
    const int tid  = threadIdx.x;
    const int lane = tid & 63;
    const int w    = tid >> 6;
    const int em   = lane & 15;
    const int q    = lane >> 4;
    const int bt   = blockIdx.x;      // 0..7
    const int ic   = blockIdx.y;      // 0..287
    const int i0   = ic * IPB;
    const int n    = em;
    const int b_loc = 4 * w + q;
    const int b_glb = bt * 16 + b_loc;

    __shared__ unsigned hatp[2 * SLOTU];   // 25.1 KB -> 6 blocks/CU

    // prefetch chunk 0 operands immediately (overlaps the pr prologue)
    Pre pre[2];
    load_i(XT, WB, pre[0], i0, bt, w, q, em);

    // ---- prologue: pr[e] for this thread's (b_glb, n) ----
    float pr[16];
    if (MODE > 0) {
        const float4* bbp = (const float4*)(Bb + (n << 4));
        const float4* ap  = (const float4*)(accA + ((size_t)b_glb << 8) + (n << 4));
        float s[16], s2 = 0.f;
        #pragma unroll
        for (int k4 = 0; k4 < 4; ++k4) {
            float4 a = ap[k4], bb = bbp[k4];
            s[4*k4+0] = a.x + bb.x; s[4*k4+1] = a.y + bb.y;
            s[4*k4+2] = a.z + bb.z; s[4*k4+3] = a.w + bb.w;
        }
        #pragma unroll
        for (int e = 0; e < 16; ++e) s2 = fmaf(s[e], s[e], s2);
        float sc = sqrtf(s2) / (1.0f + s2);
        #pragma unroll
        for (int e = 0; e < 16; ++e) pr[e] = s[e] * sc;
        if (MODE == 2) {
            const float4* ap2 = (const float4*)(accB + ((size_t)b_glb << 8) + (n << 4));
            float t[16], t2 = 0.f;
            #pragma unroll
            for (int k4 = 0; k4 < 4; ++k4) {
                float4 a = ap2[k4], bb = bbp[k4];
                t[4*k4+0] = a.x + bb.x; t[4*k4+1] = a.y + bb.y;
                t[4*k4+2] = a.z + bb.z; t[4*k4+3] = a.w + bb.w;
            }
            #pragma unroll
            for (int e = 0; e < 16; ++e) t2 = fmaf(t[e], t[e], t2);
            float sc2 = sqrtf(t2) / (1.0f + t2);
            #pragma unroll
            for (int e = 0; e < 16; ++e) pr[e] = fmaf(t[e], sc2, pr[e]);
        }
        #pragma unroll
        for (int e = 0; e < 16; ++e)
            asm volatile("" : "+v"(pr[e]));   // pin: no remat across the chunk loop
    }

    float acc[16];
    #pragma unroll
    for (int e = 0; e < 16; ++e) acc[e] = 0.f;

    commit_i(pre[0], hatp, w, q, em);              // chunk 0 -> slot 0
    load_i(XT, WB, pre[1], i0 + 1, bt, w, q, em);  // chunk 1 in flight

    #pragma unroll 1
    for (int ch = 0; ch < IPB; ++ch) {
        __syncthreads();
        if (ch + 1 < IPB)
            commit_i(pre[(ch + 1) & 1], hatp + ((ch + 1) & 1) * SLOTU, w, q, em);
        if (ch + 2 < IPB)   // refill the just-freed set; consumed 2 chunks later
            load_i(XT, WB, pre[ch & 1], i0 + ch + 2, bt, w, q, em);

        // ---- consume chunk ch (slot ch&1): e fully in-thread ----
        const unsigned* rowp = hatp + (ch & 1) * SLOTU + (size_t)b_loc * BSTRU + n * NSTRU;
        uint4 u0 = *(const uint4*)rowp;
        uint4 u1 = *(const uint4*)(rowp + 4);
        float h[16];
        {
            unsigned uu[8] = {u0.x, u0.y, u0.z, u0.w, u1.x, u1.y, u1.z, u1.w};
            #pragma unroll
            for (int j = 0; j < 8; ++j) {
                h[2*j]   = __uint_as_float(uu[j] << 16);
                h[2*j+1] = __uint_as_float(uu[j] & 0xFFFF0000u);
            }
        }
        float c;
        if (MODE > 0) {
            float lg = 0.f;
            #pragma unroll
            for (int e = 0; e < 16; ++e) lg = fmaf(pr[e], h[e], lg);
            float p = __expf(lg);                  // |lg| small -> max-free (R7-R11 proven)
            float z = dpp_sum16(p);                // softmax over n = 16-lane DPP row
            c = p * __builtin_amdgcn_rcpf(z);
        } else {
            c = 0.0625f;
        }
        #pragma unroll
        for (int e = 0; e < 16; ++e) acc[e] = fmaf(c, h[e], acc[e]);
    }

    // ---- epilogue: bf16 partial[ic][b][n][e] ----
    unsigned short* pp = partial + (((size_t)ic * B_SZ + b_glb) << 8) + (n << 4);
    uint4 o0 = {pk2(acc[0], acc[1]),   pk2(acc[2], acc[3]),
                pk2(acc[4], acc[5]),   pk2(acc[6], acc[7])};
    uint4 o1 = {pk2(acc[8], acc[9]),   pk2(acc[10], acc[11]),
                pk2(acc[12], acc[13]), pk2(acc[14], acc[15])};
    *(uint4*)pp = o0;
    *(uint4*)(pp + 8) = o1;
}

// ---- reduce 288 bf16 slices. 256 blocks x 256 thr; 64 uint positions/block;
// 4 grps x 72 slices; LDS combine; FINAL adds B + squash (8-lane DPP). ----
template<bool FINAL>
__global__ __launch_bounds__(256)
void caps_reduce(const unsigned* __restrict__ partial, const float* __restrict__ Bb,
                 float2* __restrict__ acc, float2* __restrict__ out)
{
    const int tid = threadIdx.x;
    const int ps  = tid & 63;
    const int grp = tid >> 6;
    const int pos = blockIdx.x * 64 + ps;        // uint index in [0, 16384)

    float t0 = 0.f, t1 = 0.f;
    #pragma unroll 8
    for (int k = 0; k < ICN / 4; ++k) {
        unsigned u = partial[(size_t)(grp * (ICN / 4) + k) * (OUT_ELEMS / 2) + pos];
        t0 += __uint_as_float(u << 16);
        t1 += __uint_as_float(u & 0xFFFF0000u);
    }
    __shared__ float2 red[4][64];
    red[grp][ps] = make_float2(t0, t1);
    __syncthreads();

    if (tid < 64) {
        float2 a = red[0][ps], b = red[1][ps], c = red[2][ps], d = red[3][ps];
        float v0 = a.x + b.x + c.x + d.x;
        float v1 = a.y + b.y + c.y + d.y;
        if (!FINAL) {
            acc[pos] = make_float2(v0, v1);
        } else {
            const int n = (pos >> 3) & 15, ep = pos & 7;
            float2 bb = *(const float2*)(Bb + n * 16 + 2 * ep);
            v0 += bb.x; v1 += bb.y;
            float s2 = dpp_sum8(v0 * v0 + v1 * v1);
            float sc = sqrtf(s2) / (1.0f + s2);
            out[pos] = make_float2(v0 * sc, v1 * sc);
        }
    }
}

extern "C" void kernel_launch(void* const* d_in, const int* in_sizes, int n_in,
                              void* d_out, int out_size, void* d_ws, size_t ws_size,
                              hipStream_t stream)
{
    const float* x  = (const float*)d_in[0];   // [128,1152,8]
    const float* W  = (const float*)d_in[1];   // [16,1152,16,8]
    const float* Bb = (const float*)d_in[2];   // [16,16]
    float2* out = (float2*)d_out;              // [128,16,16] fp32

    float* accA = (float*)d_ws;                                   // 128 KB
    float* accB = accA + OUT_ELEMS;                               // 128 KB
    unsigned short* WB = (unsigned short*)(accB + OUT_ELEMS);     // 4.72 MB
    unsigned short* XT = WB + (size_t)N_CAPS * IN_CAPS * DIM * 8; // 2.36 MB
    unsigned short* partial = XT + (size_t)B_SZ * IN_CAPS * 8;    // 288 x 64 KB = 18.9 MB

    conv_xw<<<1728, 256, 0, stream>>>(W, x, WB, XT);

    dim3 pg(B_SZ / 16, ICN);   // 8 x 288 = 2304 blocks (6 blocks/CU, LDS-limited)

    caps_pass<0><<<pg, 256, 0, stream>>>(XT, WB, Bb, nullptr, nullptr, partial);
    caps_reduce<false><<<256, 256, 0, stream>>>((const unsigned*)partial, Bb, (float2*)accA, nullptr);
    caps_pass<1><<<pg, 256, 0, stream>>>(XT, WB, Bb, accA, nullptr, partial);
    caps_reduce<false><<<256, 256, 0, stream>>>((const unsigned*)partial, Bb, (float2*)accB, nullptr);
    caps_pass<2><<<pg, 256, 0, stream>>>(XT, WB, Bb, accA, accB, partial);
    caps_reduce<true><<<256, 256, 0, stream>>>((const unsigned*)partial, Bb, nullptr, out);
}

// Round 13
// 147.510 us; speedup vs baseline: 3.3452x; 1.8903x over previous
//
#include <hip/hip_runtime.h>
#include <hip/hip_bf16.h>

#define B_SZ 128
#define IN_CAPS 1152
#define N_CAPS 16
#define DIM 16

#define IPB 4                         // i's per pass-block (short chunks -> big grid)
#define ICN (IN_CAPS / IPB)           // 288 partial slices
#define OUT_ELEMS (B_SZ * N_CAPS * DIM)   // 32768
// LDS hat tile (bf16 pairs, uint units): [slot(2)][b(16)][n(16)][ep(8)]
#define NSTRU 12
#define BSTRU 196
#define SLOTU (16 * BSTRU)            // 3136 uints = 12.5 KB/slot

typedef __attribute__((ext_vector_type(8))) short bf16x8;
typedef __attribute__((ext_vector_type(4))) float f32x4;

__device__ __forceinline__ unsigned short f2bf(float f) {   // RNE
    unsigned u = __float_as_uint(f);
    u = u + 0x7fffu + ((u >> 16) & 1u);
    return (unsigned short)(u >> 16);
}
__device__ __forceinline__ unsigned pk2(float lo, float hi) {
    return ((unsigned)f2bf(hi) << 16) | f2bf(lo);
}
__device__ __forceinline__ unsigned cvtpk(float lo, float hi) {
    union { __hip_bfloat162 h; unsigned u; } c;
    c.h = __float22bfloat162_rn(make_float2(lo, hi));
    return c.u;
}
__device__ __forceinline__ float dpp_sum16(float v) {
    v += __int_as_float(__builtin_amdgcn_update_dpp(0, __float_as_int(v), 0xB1, 0xF, 0xF, true));
    v += __int_as_float(__builtin_amdgcn_update_dpp(0, __float_as_int(v), 0x4E, 0xF, 0xF, true));
    v += __int_as_float(__builtin_amdgcn_update_dpp(0, __float_as_int(v), 0x124, 0xF, 0xF, true));
    v += __int_as_float(__builtin_amdgcn_update_dpp(0, __float_as_int(v), 0x128, 0xF, 0xF, true));
    return v;
}
__device__ __forceinline__ float dpp_sum8(float v) {
    v += __int_as_float(__builtin_amdgcn_update_dpp(0, __float_as_int(v), 0xB1, 0xF, 0xF, true));
    v += __int_as_float(__builtin_amdgcn_update_dpp(0, __float_as_int(v), 0x4E, 0xF, 0xF, true));
    v += __int_as_float(__builtin_amdgcn_update_dpp(0, __float_as_int(v), 0x141, 0xF, 0xF, true));
    return v;
}

// ---- prep (fused): blocks [0,1152): W -> WB bf16; [1152,1728): x -> XT[i][b][d] bf16 ----
__global__ __launch_bounds__(256)
void conv_xw(const float* __restrict__ W, const float* __restrict__ x,
             unsigned short* __restrict__ WB, unsigned short* __restrict__ XT)
{
    const int tid = threadIdx.x;
    if (blockIdx.x < 1152) {
        size_t g = (size_t)blockIdx.x * 256 + tid;
        const float4* src = (const float4*)(W + g * 8);
        float4 a = src[0], b = src[1];
        uint4 o = {pk2(a.x, a.y), pk2(a.z, a.w), pk2(b.x, b.y), pk2(b.z, b.w)};
        *(uint4*)(WB + g * 8) = o;
    } else {
        const int bx = blockIdx.x - 1152;
        const int i = bx * 2 + (tid >> 7);
        const int b = tid & 127;
        const float4* src = (const float4*)(x + ((size_t)b * IN_CAPS + i) * 8);
        float4 a = src[0], c = src[1];
        uint4 o = {pk2(a.x, a.y), pk2(a.z, a.w), pk2(c.x, c.y), pk2(c.z, c.w)};
        *(uint4*)(XT + ((size_t)i * B_SZ + b) * 8) = o;
    }
}

// Produce one i of hat into an LDS slot (R10-proven; NO register prefetch —
// R12 lesson: a 40-VGPR prefetch struct made the allocator pick VGPR=40 and
// spill 204 MB/pass to scratch. Transient-only operands stay in the ~70-live
// envelope the allocator actually grants). A = W (m=e), B = x (col=b, k>=8
// zeroed). D: col=b, regs = 4 e's -> pack bf16 -> ds_write_b64.
__device__ __forceinline__ void produce_i(
    const unsigned short* __restrict__ XT, const unsigned short* __restrict__ WB,
    unsigned* __restrict__ slot, int i, int bt, int w, int q, int em)
{
    uint4 xu = {0u, 0u, 0u, 0u};
    if (q == 0)
        xu = *(const uint4*)(XT + ((size_t)i * B_SZ + bt * 16 + em) * 8);
    union { uint4 u; bf16x8 v; } bx; bx.u = xu;
    #pragma unroll
    for (int np = 0; np < 4; ++np) {
        const int nn = 4 * w + np;
        union { uint4 u; bf16x8 v; } ax;
        ax.u = *(const uint4*)(WB + (((size_t)nn * IN_CAPS + i) * DIM + em) * 8);
        f32x4 cz = {0.f, 0.f, 0.f, 0.f};
        f32x4 d = __builtin_amdgcn_mfma_f32_16x16x32_bf16(ax.v, bx.v, cz, 0, 0, 0);
        uint2 o = {cvtpk(d[0], d[1]), cvtpk(d[2], d[3])};
        *(uint2*)(slot + (size_t)em * BSTRU + nn * NSTRU + 2 * q) = o;
    }
}

// ---- fused routing pass ----
// R11 diagnosis: chunk loop is latency-serial; wall ~ 1/resident-waves.
// R13 = R10 internals (direct produce, dbuf LDS, DPP softmax, e-in-thread
// consumer) at R12's occupancy (IPB=4, grid 2304 -> 6 blocks/CU, 24 waves/CU).
// MODE 0: c=1/16.  MODE 1: pr = squash(accA+B).  MODE 2: pr = sq(accA+B)+sq(accB+B).
template<int MODE>
__global__ __launch_bounds__(256)
void caps_pass(const unsigned short* __restrict__ XT, const unsigned short* __restrict__ WB,
               const float* __restrict__ Bb,
               const float* __restrict__ accA, const float* __restrict__ accB,
               unsigned short* __restrict__ partial)
{
    const int tid  = threadIdx.x;
    const int lane = tid & 63;
    const int w    = tid >> 6;
    const int em   = lane & 15;
    const int q    = lane >> 4;
    const int bt   = blockIdx.x;      // 0..7  (x-fastest: 8 sibling blocks share the WB slice in L2/L3)
    const int ic   = blockIdx.y;      // 0..287
    const int i0   = ic * IPB;
    const int n    = em;
    const int b_loc = 4 * w + q;
    const int b_glb = bt * 16 + b_loc;

    __shared__ unsigned hatp[2 * SLOTU];   // 25.1 KB -> 6 blocks/CU (LDS-limited)

    produce_i(XT, WB, hatp, i0, bt, w, q, em);   // chunk 0 -> slot 0 (overlaps prologue)

    // ---- prologue: pr[e] for this thread's (b_glb, n) ----
    float pr[16];
    if (MODE > 0) {
        const float4* bbp = (const float4*)(Bb + (n << 4));
        const float4* ap  = (const float4*)(accA + ((size_t)b_glb << 8) + (n << 4));
        float s[16], s2 = 0.f;
        #pragma unroll
        for (int k4 = 0; k4 < 4; ++k4) {
            float4 a = ap[k4], bb = bbp[k4];
            s[4*k4+0] = a.x + bb.x; s[4*k4+1] = a.y + bb.y;
            s[4*k4+2] = a.z + bb.z; s[4*k4+3] = a.w + bb.w;
        }
        #pragma unroll
        for (int e = 0; e < 16; ++e) s2 = fmaf(s[e], s[e], s2);
        float sc = sqrtf(s2) / (1.0f + s2);
        #pragma unroll
        for (int e = 0; e < 16; ++e) pr[e] = s[e] * sc;
        if (MODE == 2) {
            const float4* ap2 = (const float4*)(accB + ((size_t)b_glb << 8) + (n << 4));
            float t[16], t2 = 0.f;
            #pragma unroll
            for (int k4 = 0; k4 < 4; ++k4) {
                float4 a = ap2[k4], bb = bbp[k4];
                t[4*k4+0] = a.x + bb.x; t[4*k4+1] = a.y + bb.y;
                t[4*k4+2] = a.z + bb.z; t[4*k4+3] = a.w + bb.w;
            }
            #pragma unroll
            for (int e = 0; e < 16; ++e) t2 = fmaf(t[e], t[e], t2);
            float sc2 = sqrtf(t2) / (1.0f + t2);
            #pragma unroll
            for (int e = 0; e < 16; ++e) pr[e] = fmaf(t[e], sc2, pr[e]);
        }
        #pragma unroll
        for (int e = 0; e < 16; ++e)
            asm volatile("" : "+v"(pr[e]));   // pin: no remat across the chunk loop
    }

    float acc[16];
    #pragma unroll
    for (int e = 0; e < 16; ++e) acc[e] = 0.f;

    #pragma unroll 1
    for (int ch = 0; ch < IPB; ++ch) {
        __syncthreads();
        if (ch + 1 < IPB)   // produce next chunk into the other slot, overlapping consume
            produce_i(XT, WB, hatp + ((ch + 1) & 1) * SLOTU, i0 + ch + 1, bt, w, q, em);

        // ---- consume chunk ch (slot ch&1): e fully in-thread ----
        const unsigned* rowp = hatp + (ch & 1) * SLOTU + (size_t)b_loc * BSTRU + n * NSTRU;
        uint4 u0 = *(const uint4*)rowp;
        uint4 u1 = *(const uint4*)(rowp + 4);
        float h[16];
        {
            unsigned uu[8] = {u0.x, u0.y, u0.z, u0.w, u1.x, u1.y, u1.z, u1.w};
            #pragma unroll
            for (int j = 0; j < 8; ++j) {
                h[2*j]   = __uint_as_float(uu[j] << 16);
                h[2*j+1] = __uint_as_float(uu[j] & 0xFFFF0000u);
            }
        }
        float c;
        if (MODE > 0) {
            float lg = 0.f;
            #pragma unroll
            for (int e = 0; e < 16; ++e) lg = fmaf(pr[e], h[e], lg);
            float p = __expf(lg);                  // |lg| small -> max-free (R7-R12 proven)
            float z = dpp_sum16(p);                // softmax over n = 16-lane DPP row
            c = p * __builtin_amdgcn_rcpf(z);
        } else {
            c = 0.0625f;
        }
        #pragma unroll
        for (int e = 0; e < 16; ++e) acc[e] = fmaf(c, h[e], acc[e]);
    }

    // ---- epilogue: bf16 partial[ic][b][n][e] ----
    unsigned short* pp = partial + (((size_t)ic * B_SZ + b_glb) << 8) + (n << 4);
    uint4 o0 = {pk2(acc[0], acc[1]),   pk2(acc[2], acc[3]),
                pk2(acc[4], acc[5]),   pk2(acc[6], acc[7])};
    uint4 o1 = {pk2(acc[8], acc[9]),   pk2(acc[10], acc[11]),
                pk2(acc[12], acc[13]), pk2(acc[14], acc[15])};
    *(uint4*)pp = o0;
    *(uint4*)(pp + 8) = o1;
}

// ---- reduce 288 bf16 slices. 256 blocks x 256 thr; 64 uint positions/block;
// 4 grps x 72 slices; LDS combine; FINAL adds B + squash (8-lane DPP). ----
template<bool FINAL>
__global__ __launch_bounds__(256)
void caps_reduce(const unsigned* __restrict__ partial, const float* __restrict__ Bb,
                 float2* __restrict__ acc, float2* __restrict__ out)
{
    const int tid = threadIdx.x;
    const int ps  = tid & 63;
    const int grp = tid >> 6;
    const int pos = blockIdx.x * 64 + ps;        // uint index in [0, 16384)

    float t0 = 0.f, t1 = 0.f;
    #pragma unroll 8
    for (int k = 0; k < ICN / 4; ++k) {
        unsigned u = partial[(size_t)(grp * (ICN / 4) + k) * (OUT_ELEMS / 2) + pos];
        t0 += __uint_as_float(u << 16);
        t1 += __uint_as_float(u & 0xFFFF0000u);
    }
    __shared__ float2 red[4][64];
    red[grp][ps] = make_float2(t0, t1);
    __syncthreads();

    if (tid < 64) {
        float2 a = red[0][ps], b = red[1][ps], c = red[2][ps], d = red[3][ps];
        float v0 = a.x + b.x + c.x + d.x;
        float v1 = a.y + b.y + c.y + d.y;
        if (!FINAL) {
            acc[pos] = make_float2(v0, v1);
        } else {
            const int n = (pos >> 3) & 15, ep = pos & 7;
            float2 bb = *(const float2*)(Bb + n * 16 + 2 * ep);
            v0 += bb.x; v1 += bb.y;
            float s2 = dpp_sum8(v0 * v0 + v1 * v1);
            float sc = sqrtf(s2) / (1.0f + s2);
            out[pos] = make_float2(v0 * sc, v1 * sc);
        }
    }
}

extern "C" void kernel_launch(void* const* d_in, const int* in_sizes, int n_in,
                              void* d_out, int out_size, void* d_ws, size_t ws_size,
                              hipStream_t stream)
{
    const float* x  = (const float*)d_in[0];   // [128,1152,8]
    const float* W  = (const float*)d_in[1];   // [16,1152,16,8]
    const float* Bb = (const float*)d_in[2];   // [16,16]
    float2* out = (float2*)d_out;              // [128,16,16] fp32

    float* accA = (float*)d_ws;                                   // 128 KB
    float* accB = accA + OUT_ELEMS;                               // 128 KB
    unsigned short* WB = (unsigned short*)(accB + OUT_ELEMS);     // 4.72 MB
    unsigned short* XT = WB + (size_t)N_CAPS * IN_CAPS * DIM * 8; // 2.36 MB
    unsigned short* partial = XT + (size_t)B_SZ * IN_CAPS * 8;    // 288 x 64 KB = 18.9 MB

    conv_xw<<<1728, 256, 0, stream>>>(W, x, WB, XT);

    dim3 pg(B_SZ / 16, ICN);   // 8 x 288 = 2304 blocks (6 blocks/CU, LDS-limited)

    caps_pass<0><<<pg, 256, 0, stream>>>(XT, WB, Bb, nullptr, nullptr, partial);
    caps_reduce<false><<<256, 256, 0, stream>>>((const unsigned*)partial, Bb, (float2*)accA, nullptr);
    caps_pass<1><<<pg, 256, 0, stream>>>(XT, WB, Bb, accA, nullptr, partial);
    caps_reduce<false><<<256, 256, 0, stream>>>((const unsigned*)partial, Bb, (float2*)accB, nullptr);
    caps_pass<2><<<pg, 256, 0, stream>>>(XT, WB, Bb, accA, accB, partial);
    caps_reduce<true><<<256, 256, 0, stream>>>((const unsigned*)partial, Bb, nullptr, out);
}